// Round 7
// baseline (48.528 us; speedup 1.0000x reference)
//
#include <hip/hip_runtime.h>
#include <hip/hip_fp16.h>

// Problem constants
#define B_TOT 65536
#define I_DIM 128     // K
#define N_DIM 256
#define BM    32      // batch rows per block
#define NTHR  256

typedef __attribute__((ext_vector_type(8))) _Float16 half8;
typedef __attribute__((ext_vector_type(4))) _Float16 half4;
typedef __attribute__((ext_vector_type(4))) float    f32x4;

__device__ inline float fast_exp2(float x) {
#if __has_builtin(__builtin_amdgcn_exp2f)
  return __builtin_amdgcn_exp2f(x);
#else
  return exp2f(x);
#endif
}
__device__ inline float fast_rcp(float x) {
#if __has_builtin(__builtin_amdgcn_rcpf)
  return __builtin_amdgcn_rcpf(x);
#else
  return 1.0f / x;
#endif
}

// ws layout:
//   [0, 65536)   : W_in as fp16, row-major [256][128] linear (L2-resident)
//   [65536, +5KB): per-neuron params: wm[256], bias[256], nsl[256], A[256], nt[256]
__global__ void prep_kernel(const float* __restrict__ W_in, const float* __restrict__ w_rec,
                            const void* __restrict__ mask, const float* __restrict__ bias,
                            const float* __restrict__ tau, const float* __restrict__ Aamp,
                            const float* __restrict__ sigma, char* __restrict__ ws) {
  __shared__ int flag;
  const int t = threadIdx.x;

  if (blockIdx.x == 0) {
    // ---- mask dtype detection: reads stay within 256 bytes under either layout ----
    if (t == 0) flag = 0;
    __syncthreads();
    if (t < 64) {
      int w = ((const int*)mask)[t];
      if (w != 0 && w != 1) atomicOr(&flag, 1);
    }
    __syncthreads();
    const bool as_bytes = (flag != 0);
    const int nn = t;  // one neuron per thread
    float mv = as_bytes ? (float)(((const unsigned char*)mask)[nn])
                        : (float)(((const int*)mask)[nn]);
    float* P = (float*)(ws + 65536);
    P[nn]         = w_rec[nn] * mv;                          // wm (sparsity-masked)
    P[256 + nn]   = bias[nn];                                 // bias
    P[512 + nn]   = -sigma[nn] * 1.44269504088896340736f;     // -sigma*log2(e)
    P[768 + nn]   = Aamp[nn];                                 // A
    P[1024 + nn]  = -1.0f / tau[nn];                          // -1/tau
  }

  // ---- W_in fp32 -> fp16, linear row-major, coalesced ----
  int f4 = blockIdx.x * NTHR + t;            // 0..8191 float4s (256*128/4)
  float4 v = ((const float4*)W_in)[f4];
  half4 hv;
  hv[0] = (_Float16)v.x; hv[1] = (_Float16)v.y;
  hv[2] = (_Float16)v.z; hv[3] = (_Float16)v.w;
  ((half4*)ws)[f4] = hv;
}

// RK4 for one element. dx/dt = -x/tau + sigmoid(sigma*(ic + x*wm + b))*(A - x)
__device__ inline float rk4_one(float ic, float bi, float wm, float nsl,
                                float Aa, float nt, float h0) {
  const float icb = ic + bi;
  auto ode = [&](float s) {
    float tot = fmaf(s, wm, icb);
    float e   = fast_exp2(nsl * tot);         // exp(-sigma*tot)
    float f   = fast_rcp(1.0f + e);           // sigmoid
    return fmaf(f, Aa - s, s * nt);
  };
  float k1 = ode(h0);
  float k2 = ode(fmaf(0.5f, k1, h0));
  float k3 = ode(fmaf(0.5f, k2, h0));
  float k4 = ode(h0 + k3);
  return fmaf(fmaf(2.0f, k2 + k3, k1 + k4), 0.16666666666666666f, h0);
}

// 16 KB LDS (sA and sIC UNIONED - temporally disjoint), min-waves 8:
// VGPR capped at 64 -> 8 blocks/CU -> 32 waves/CU, whole grid co-resident.
__launch_bounds__(NTHR, 8)
__global__ void liquid_kernel(const float* __restrict__ x, const float* __restrict__ h,
                              const char* __restrict__ ws, float* __restrict__ out) {
  // Phase 1 (sA) : x tile [32][128] fp16, XOR-swizzled 16B chunks (8 KB of 16)
  // Phase 2 (sIC): ic [32][256] fp16, XOR-swizzled 8-half chunks (16 KB)
  __shared__ char smem[16384];
  char* sA  = smem;
  char* sIC = smem;

  const int t    = threadIdx.x;
  const int b0   = blockIdx.x * BM;
  const int wave = t >> 6;
  const int lane = t & 63;
  const int lr   = lane & 15;   // fragment row/col index
  const int lk   = lane >> 4;   // k-chunk / acc-row-group index
  const int col4 = t & 63;      // epilogue neuron-quad id
  const int nbase = col4 * 4;
  const char* wg = ws;          // W fp16 [256][128] linear

  // ---- stage x tile -> sA (fp16, swizzled): 512 chunks, 2 per thread ----
  {
    const float4* xg = (const float4*)(x + (size_t)b0 * I_DIM);
#pragma unroll
    for (int i = 0; i < 2; ++i) {
      int c   = t + i * NTHR;        // 16B-chunk index in [32][16]
      int row = c >> 4;
      int cir = c & 15;
      float4 v0 = xg[row * 32 + cir * 2];
      float4 v1 = xg[row * 32 + cir * 2 + 1];
      half8 hv;
      hv[0] = (_Float16)v0.x; hv[1] = (_Float16)v0.y;
      hv[2] = (_Float16)v0.z; hv[3] = (_Float16)v0.w;
      hv[4] = (_Float16)v1.x; hv[5] = (_Float16)v1.y;
      hv[6] = (_Float16)v1.z; hv[7] = (_Float16)v1.w;
      *(half8*)(sA + row * 256 + ((cir ^ (row & 7)) << 4)) = hv;
    }
  }
  __syncthreads();

  // ---- GEMM: D = W · x^T. Wave owns neurons [wave*64,+64) x batches [0,32).
  // acc[n][m][r]: neuron wave*64+n*16+lk*4+r, batch m*16+lr.
  // No W-prefetch registers: TLP (32 waves/CU) hides L2 latency. ----
  f32x4 acc[4][2] = {};
#pragma unroll
  for (int k = 0; k < 4; ++k) {
    half8 bx[2];
#pragma unroll
    for (int m = 0; m < 2; ++m) {
      int row   = m * 16 + lr;         // batch row
      int chunk = k * 4 + lk;
      bx[m] = *(const half8*)(sA + row * 256 + ((chunk ^ (row & 7)) << 4));
    }
#pragma unroll
    for (int n = 0; n < 4; ++n) {
      int neuron = wave * 64 + n * 16 + lr;
      half8 aw = *(const half8*)(wg + neuron * 256 + (k * 4 + lk) * 16);
#pragma unroll
      for (int m = 0; m < 2; ++m)
        acc[n][m] = __builtin_amdgcn_mfma_f32_16x16x32_f16(aw, bx[m], acc[n][m], 0, 0, 0);
    }
  }
  __syncthreads();   // all waves done READING sA before sIC overwrites it

  // ---- transpose acc -> sIC as fp16 (half4 stores, XOR-swizzled) ----
#pragma unroll
  for (int n = 0; n < 4; ++n)
#pragma unroll
    for (int m = 0; m < 2; ++m) {
      const int nb = wave * 64 + n * 16 + lk * 4;
      const int bm = m * 16 + lr;
      const int chunk = nb >> 3;
      const int sub = nb & 7;
      half4 hv;
      hv[0] = (_Float16)acc[n][m][0]; hv[1] = (_Float16)acc[n][m][1];
      hv[2] = (_Float16)acc[n][m][2]; hv[3] = (_Float16)acc[n][m][3];
      *(half4*)(sIC + (bm * 256 + ((chunk ^ (bm & 7)) << 3) + sub) * 2) = hv;
    }

  // ---- per-thread params: 4 consecutive neurons (overlap the barrier wait) ----
  const float* P = (const float*)(ws + 65536);
  const float4 wm4 = *(const float4*)(P + nbase);
  const float4 bi4 = *(const float4*)(P + 256 + nbase);
  const float4 sl4 = *(const float4*)(P + 512 + nbase);
  const float4 Aa4 = *(const float4*)(P + 768 + nbase);
  const float4 nt4 = *(const float4*)(P + 1024 + nbase);
  __syncthreads();

  // ---- fused RK4 epilogue: per instr one full row, 1KB contiguous h/out ----
#pragma unroll
  for (int i = 0; i < 8; ++i) {
    const int row = wave + 4 * i;                  // uniform within wave
    const int chunk = col4 >> 1;
    const int sub = (col4 & 1) * 4;
    half4 ic4 = *(const half4*)(sIC + (row * 256 + ((chunk ^ (row & 7)) << 3) + sub) * 2);
    const size_t off = (size_t)(b0 + row) * N_DIM + nbase;
    f32x4 h4 = *(const f32x4*)(h + off);
    f32x4 o4;
    o4[0] = rk4_one((float)ic4[0], bi4.x, wm4.x, sl4.x, Aa4.x, nt4.x, h4[0]);
    o4[1] = rk4_one((float)ic4[1], bi4.y, wm4.y, sl4.y, Aa4.y, nt4.y, h4[1]);
    o4[2] = rk4_one((float)ic4[2], bi4.z, wm4.z, sl4.z, Aa4.z, nt4.z, h4[2]);
    o4[3] = rk4_one((float)ic4[3], bi4.w, wm4.w, sl4.w, Aa4.w, nt4.w, h4[3]);
    __builtin_nontemporal_store(o4, (f32x4*)(out + off));   // streaming write
  }
}

extern "C" void kernel_launch(void* const* d_in, const int* in_sizes, int n_in,
                              void* d_out, int out_size, void* d_ws, size_t ws_size,
                              hipStream_t stream) {
  const float* x     = (const float*)d_in[0];
  const float* h     = (const float*)d_in[1];
  const float* W_in  = (const float*)d_in[2];
  const float* w_rec = (const float*)d_in[3];
  const void*  mask  = d_in[4];
  const float* bias  = (const float*)d_in[5];
  const float* tau   = (const float*)d_in[6];
  const float* A     = (const float*)d_in[7];
  const float* sigma = (const float*)d_in[8];
  float* out = (float*)d_out;
  char*  ws  = (char*)d_ws;

  prep_kernel<<<32, NTHR, 0, stream>>>(W_in, w_rec, mask, bias, tau, A, sigma, ws);
  liquid_kernel<<<B_TOT / BM, NTHR, 0, stream>>>(x, h, ws, out);
}

// Round 8
// 41.901 us; speedup vs baseline: 1.1582x; 1.1582x over previous
//
#include <hip/hip_runtime.h>
#include <hip/hip_fp16.h>

// Problem constants
#define B_TOT 65536
#define I_DIM 128     // K
#define N_DIM 256
#define BM    64      // batch rows per block
#define NTHR  256

typedef __attribute__((ext_vector_type(8))) _Float16 half8;
typedef __attribute__((ext_vector_type(4))) _Float16 half4;
typedef __attribute__((ext_vector_type(4))) float    f32x4;

__device__ inline float fast_exp2(float x) {
#if __has_builtin(__builtin_amdgcn_exp2f)
  return __builtin_amdgcn_exp2f(x);
#else
  return exp2f(x);
#endif
}
__device__ inline float fast_rcp(float x) {
#if __has_builtin(__builtin_amdgcn_rcpf)
  return __builtin_amdgcn_rcpf(x);
#else
  return 1.0f / x;
#endif
}

// ws layout:
//   [0, 65536)   : W_in as fp16, row-major [256][128] linear (L2-resident)
//   [65536, +5KB): per-neuron params: wm[256], bias[256], nsl[256], A[256], nt[256]
__global__ void prep_kernel(const float* __restrict__ W_in, const float* __restrict__ w_rec,
                            const void* __restrict__ mask, const float* __restrict__ bias,
                            const float* __restrict__ tau, const float* __restrict__ Aamp,
                            const float* __restrict__ sigma, char* __restrict__ ws) {
  __shared__ int flag;
  const int t = threadIdx.x;

  if (blockIdx.x == 0) {
    // ---- mask dtype detection: reads stay within 256 bytes under either layout ----
    if (t == 0) flag = 0;
    __syncthreads();
    if (t < 64) {
      int w = ((const int*)mask)[t];
      if (w != 0 && w != 1) atomicOr(&flag, 1);
    }
    __syncthreads();
    const bool as_bytes = (flag != 0);
    const int nn = t;  // one neuron per thread
    float mv = as_bytes ? (float)(((const unsigned char*)mask)[nn])
                        : (float)(((const int*)mask)[nn]);
    float* P = (float*)(ws + 65536);
    P[nn]         = w_rec[nn] * mv;                          // wm (sparsity-masked)
    P[256 + nn]   = bias[nn];                                 // bias
    P[512 + nn]   = -sigma[nn] * 1.44269504088896340736f;     // -sigma*log2(e)
    P[768 + nn]   = Aamp[nn];                                 // A
    P[1024 + nn]  = -1.0f / tau[nn];                          // -1/tau
  }

  // ---- W_in fp32 -> fp16, linear row-major, coalesced ----
  int f4 = blockIdx.x * NTHR + t;            // 0..8191 float4s (256*128/4)
  float4 v = ((const float4*)W_in)[f4];
  half4 hv;
  hv[0] = (_Float16)v.x; hv[1] = (_Float16)v.y;
  hv[2] = (_Float16)v.z; hv[3] = (_Float16)v.w;
  ((half4*)ws)[f4] = hv;
}

// RK4 for one element. dx/dt = -x/tau + sigmoid(sigma*(ic + x*wm + b))*(A - x)
__device__ inline float rk4_one(float ic, float bi, float wm, float nsl,
                                float Aa, float nt, float h0) {
  const float icb = ic + bi;
  auto ode = [&](float s) {
    float tot = fmaf(s, wm, icb);
    float e   = fast_exp2(nsl * tot);         // exp(-sigma*tot)
    float f   = fast_rcp(1.0f + e);           // sigmoid
    return fmaf(f, Aa - s, s * nt);
  };
  float k1 = ode(h0);
  float k2 = ode(fmaf(0.5f, k1, h0));
  float k3 = ode(fmaf(0.5f, k2, h0));
  float k4 = ode(h0 + k3);
  return fmaf(fmaf(2.0f, k2 + k3, k1 + k4), 0.16666666666666666f, h0);
}

// 32 KB LDS (sA unioned with sIC), 4 blocks/CU (128 unified regs/wave).
__launch_bounds__(NTHR, 4)
__global__ void liquid_kernel(const float* __restrict__ x, const float* __restrict__ h,
                              const char* __restrict__ ws, float* __restrict__ out) {
  // Phase 1 (sA) : x tile [64][128] fp16, XOR-swizzled 16B chunks (16 KB of 32)
  // Phase 2 (sIC): ic [64][256] fp16, XOR-swizzled 8-half chunks (32 KB)
  __shared__ char smem[32768];
  char* sA  = smem;
  char* sIC = smem;

  const int t    = threadIdx.x;
  const int b0   = blockIdx.x * BM;
  const int wave = t >> 6;
  const int lane = t & 63;
  const int lr   = lane & 15;   // fragment row/col index
  const int lk   = lane >> 4;   // k-chunk / acc-row-group index
  const int col4 = t & 63;      // epilogue neuron-quad id
  const int nbase = col4 * 4;
  const char* wg = ws;          // W fp16 [256][128] linear

  // ---- stage x tile -> sA (fp16, swizzled): 1024 chunks, 4 per thread ----
  {
    const float4* xg = (const float4*)(x + (size_t)b0 * I_DIM);
#pragma unroll
    for (int i = 0; i < 4; ++i) {
      int c   = t + i * NTHR;        // 16B-chunk index in [64][16]
      int row = c >> 4;
      int cir = c & 15;
      float4 v0 = xg[row * 32 + cir * 2];
      float4 v1 = xg[row * 32 + cir * 2 + 1];
      half8 hv;
      hv[0] = (_Float16)v0.x; hv[1] = (_Float16)v0.y;
      hv[2] = (_Float16)v0.z; hv[3] = (_Float16)v0.w;
      hv[4] = (_Float16)v1.x; hv[5] = (_Float16)v1.y;
      hv[6] = (_Float16)v1.z; hv[7] = (_Float16)v1.w;
      *(half8*)(sA + row * 256 + ((cir ^ (row & 7)) << 4)) = hv;
    }
  }

  // W fragments for k=0 (L2), issued before the barrier wait
  half8 awc[4], awn[4];
#pragma unroll
  for (int n = 0; n < 4; ++n) {
    int neuron = wave * 64 + n * 16 + lr;
    awc[n] = *(const half8*)(wg + neuron * 256 + lk * 16);
  }
  __syncthreads();

  // ---- GEMM: D = W · x^T. Wave owns neurons [wave*64,+64) x batches [0,64).
  // acc[n][m][r]: neuron wave*64+n*16+lk*4+r, batch m*16+lr. ----
  f32x4 acc[4][4] = {};
#pragma unroll
  for (int k = 0; k < 4; ++k) {
    if (k < 3) {                       // rotating 1-deep W prefetch
#pragma unroll
      for (int n = 0; n < 4; ++n) {
        int neuron = wave * 64 + n * 16 + lr;
        awn[n] = *(const half8*)(wg + neuron * 256 + ((k + 1) * 4 + lk) * 16);
      }
    }
    half8 bx[4];
#pragma unroll
    for (int m = 0; m < 4; ++m) {
      int row   = m * 16 + lr;         // batch row
      int chunk = k * 4 + lk;
      bx[m] = *(const half8*)(sA + row * 256 + ((chunk ^ (row & 7)) << 4));
    }
#pragma unroll
    for (int n = 0; n < 4; ++n)
#pragma unroll
      for (int m = 0; m < 4; ++m)
        acc[n][m] = __builtin_amdgcn_mfma_f32_16x16x32_f16(awc[n], bx[m], acc[n][m], 0, 0, 0);
    if (k < 3) {
#pragma unroll
      for (int n = 0; n < 4; ++n) awc[n] = awn[n];
    }
  }
  __syncthreads();   // all waves done READING sA before sIC overwrites it

  // ---- transpose acc -> sIC as fp16 (half4 stores, XOR-swizzled) ----
#pragma unroll
  for (int n = 0; n < 4; ++n)
#pragma unroll
    for (int m = 0; m < 4; ++m) {
      const int nb = wave * 64 + n * 16 + lk * 4;
      const int bm = m * 16 + lr;
      const int chunk = nb >> 3;
      const int sub = nb & 7;
      half4 hv;
      hv[0] = (_Float16)acc[n][m][0]; hv[1] = (_Float16)acc[n][m][1];
      hv[2] = (_Float16)acc[n][m][2]; hv[3] = (_Float16)acc[n][m][3];
      *(half4*)(sIC + (bm * 256 + ((chunk ^ (bm & 7)) << 3) + sub) * 2) = hv;
    }

  // ---- per-thread params: 4 consecutive neurons (overlap the barrier wait) ----
  const float* P = (const float*)(ws + 65536);
  const float4 wm4 = *(const float4*)(P + nbase);
  const float4 bi4 = *(const float4*)(P + 256 + nbase);
  const float4 sl4 = *(const float4*)(P + 512 + nbase);
  const float4 Aa4 = *(const float4*)(P + 768 + nbase);
  const float4 nt4 = *(const float4*)(P + 1024 + nbase);
  __syncthreads();

  // ---- fused RK4 epilogue: 16 rows/thread in 4 batches of 4.
  //      Loads batched (latency paid 4x not 16x); 1KB contiguous h/out rows. ----
  const int chunk = col4 >> 1;
  const int sub   = (col4 & 1) * 4;
#pragma unroll
  for (int g = 0; g < 4; ++g) {
    int   rows[4];
    half4 ic4[4];
    f32x4 h4[4];
#pragma unroll
    for (int j = 0; j < 4; ++j) {
      rows[j] = wave + 16 * g + 4 * j;           // uniform within wave
      ic4[j] = *(const half4*)(sIC + (rows[j] * 256 + ((chunk ^ (rows[j] & 7)) << 3) + sub) * 2);
      h4[j]  = *(const f32x4*)(h + (size_t)(b0 + rows[j]) * N_DIM + nbase);
    }
#pragma unroll
    for (int j = 0; j < 4; ++j) {
      const size_t off = (size_t)(b0 + rows[j]) * N_DIM + nbase;
      f32x4 o4;
      o4[0] = rk4_one((float)ic4[j][0], bi4.x, wm4.x, sl4.x, Aa4.x, nt4.x, h4[j][0]);
      o4[1] = rk4_one((float)ic4[j][1], bi4.y, wm4.y, sl4.y, Aa4.y, nt4.y, h4[j][1]);
      o4[2] = rk4_one((float)ic4[j][2], bi4.z, wm4.z, sl4.z, Aa4.z, nt4.z, h4[j][2]);
      o4[3] = rk4_one((float)ic4[j][3], bi4.w, wm4.w, sl4.w, Aa4.w, nt4.w, h4[j][3]);
      __builtin_nontemporal_store(o4, (f32x4*)(out + off));   // streaming write
    }
  }
}

extern "C" void kernel_launch(void* const* d_in, const int* in_sizes, int n_in,
                              void* d_out, int out_size, void* d_ws, size_t ws_size,
                              hipStream_t stream) {
  const float* x     = (const float*)d_in[0];
  const float* h     = (const float*)d_in[1];
  const float* W_in  = (const float*)d_in[2];
  const float* w_rec = (const float*)d_in[3];
  const void*  mask  = d_in[4];
  const float* bias  = (const float*)d_in[5];
  const float* tau   = (const float*)d_in[6];
  const float* A     = (const float*)d_in[7];
  const float* sigma = (const float*)d_in[8];
  float* out = (float*)d_out;
  char*  ws  = (char*)d_ws;

  prep_kernel<<<32, NTHR, 0, stream>>>(W_in, w_rec, mask, bias, tau, A, sigma, ws);
  liquid_kernel<<<B_TOT / BM, NTHR, 0, stream>>>(x, h, ws, out);
}